// Round 7
// baseline (198.921 us; speedup 1.0000x reference)
//
#include <hip/hip_runtime.h>

#define DEV static __device__ __forceinline__

typedef __attribute__((ext_vector_type(4))) float f32x4;
typedef __attribute__((ext_vector_type(8))) __bf16 bfv8;
typedef __attribute__((ext_vector_type(8))) short s8v;
typedef __attribute__((ext_vector_type(4))) short s4v;

DEV short f2bf(float f) {
    unsigned u = __float_as_uint(f);
    u = (u + 0x7fffu + ((u >> 16) & 1u)) >> 16;
    return (short)u;
}
DEV float bf2f(short s) { return __uint_as_float(((unsigned)(unsigned short)s) << 16); }

DEV void gload16(const void* g, void* l) {
    __builtin_amdgcn_global_load_lds(
        (const __attribute__((address_space(1))) void*)g,
        (__attribute__((address_space(3))) void*)l, 16, 0, 0);
}

DEV f32x4 mfma16(bfv8 a, bfv8 b, f32x4 c) {
    return __builtin_amdgcn_mfma_f32_16x16x32_bf16(a, b, c, 0, 0, 0);
}

DEV float max3f(float a, float b, float c) {
    float d;
    asm("v_max3_f32 %0, %1, %2, %3" : "=v"(d) : "v"(a), "v"(b), "v"(c));
    return d;
}
DEV unsigned cvtpk(float lo, float hi) {
    unsigned w;
    asm("v_cvt_pk_bf16_f32 %0, %1, %2" : "=v"(w) : "v"(lo), "v"(hi));
    return w;
}

// LDS tile layout (GEMM): [row][8 slots of 8 bf16], physical slot = slot ^ (row&7)
DEV bfv8 ldsfrag(const short* base, int row, int slog) {
    int sp = slog ^ (row & 7);
    return *reinterpret_cast<const bfv8*>(base + row * 64 + sp * 8);
}

// ---------------- f32 -> bf16 elementwise (8 elems/thread, exact-fit grid) ----
__global__ void k_cvt(const float* __restrict__ in, short* __restrict__ out, float s) {
    int i = blockIdx.x * blockDim.x + threadIdx.x;
    const float4* p = (const float4*)in + (size_t)i * 2;
    float4 a = p[0], b = p[1];
    s8v o;
    o[0] = f2bf(a.x * s); o[1] = f2bf(a.y * s); o[2] = f2bf(a.z * s); o[3] = f2bf(a.w * s);
    o[4] = f2bf(b.x * s); o[5] = f2bf(b.y * s); o[6] = f2bf(b.z * s); o[7] = f2bf(b.w * s);
    reinterpret_cast<s8v*>(out)[i] = o;
}

// ---------------- all four W [1024x1024] f32 -> Wt [n][k] bf16 (z selects) -----
__global__ void k_transpose4(
    const float* __restrict__ W0, const float* __restrict__ W1,
    const float* __restrict__ W2, const float* __restrict__ W3,
    short* __restrict__ T0, short* __restrict__ T1,
    short* __restrict__ T2, short* __restrict__ T3, float s0)
{
    __shared__ float tl[32][33];
    const int z = blockIdx.z;
    const float* W = z == 0 ? W0 : z == 1 ? W1 : z == 2 ? W2 : W3;
    short* Wt = z == 0 ? T0 : z == 1 ? T1 : z == 2 ? T2 : T3;
    const float s = z == 0 ? s0 : 1.f;
    int tx = threadIdx.x & 31, ty = threadIdx.x >> 5;
    int nb = blockIdx.x * 32, kb = blockIdx.y * 32;
#pragma unroll
    for (int i = 0; i < 4; i++)
        tl[ty + i * 8][tx] = W[(kb + ty + i * 8) * 1024 + nb + tx];
    __syncthreads();
#pragma unroll
    for (int i = 0; i < 4; i++)
        Wt[(nb + ty + i * 8) * 1024 + kb + tx] = f2bf(tl[tx][ty + i * 8] * s);
}

// ---------------- GEMM core (BM=64 BN=128 BK=64, 4 waves 2Mx2N) ---------------
// epi 0: bf16 out [B,H,S,Hd]; epi 1: bf16 out [B,H,Hd,S] (V^T); epi 2: f32 row-major.
template <int EPI>
DEV void gemm_body(const short* __restrict__ A, const short* __restrict__ Bt,
                   const float* __restrict__ bias, void* __restrict__ outp,
                   float bscale, int row0, int col0, short* As, short* Bs)
{
    const int t = threadIdx.x, lane = t & 63;
    const int wv = t >> 6, wr = wv >> 1, wc = wv & 1;
    const int g = lane >> 4, c = lane & 15;

    const f32x4 z4 = {0.f, 0.f, 0.f, 0.f};
    f32x4 acc[2][4];
#pragma unroll
    for (int m = 0; m < 2; m++)
#pragma unroll
        for (int n = 0; n < 4; n++) acc[m][n] = z4;

    for (int kt = 0; kt < 16; ++kt) {
        const int k0 = kt * 64;
        const short* Ag = A + row0 * 1024 + k0;
        const short* Bg = Bt + col0 * 1024 + k0;
#pragma unroll
        for (int j = 0; j < 2; j++) {
            int idx = j * 256 + t;
            int row = idx >> 3, sp = idx & 7, sl = sp ^ (row & 7);
            gload16(Ag + row * 1024 + sl * 8, As + idx * 8);
        }
#pragma unroll
        for (int j = 0; j < 4; j++) {
            int idx = j * 256 + t;
            int row = idx >> 3, sp = idx & 7, sl = sp ^ (row & 7);
            gload16(Bg + row * 1024 + sl * 8, Bs + idx * 8);
        }
        __syncthreads();

        bfv8 af[2][2], bfr[4][2];
#pragma unroll
        for (int m = 0; m < 2; m++)
#pragma unroll
            for (int ks = 0; ks < 2; ks++)
                af[m][ks] = ldsfrag(As, wr * 32 + m * 16 + c, ks * 4 + g);
#pragma unroll
        for (int n = 0; n < 4; n++)
#pragma unroll
            for (int ks = 0; ks < 2; ks++)
                bfr[n][ks] = ldsfrag(Bs, wc * 64 + n * 16 + c, ks * 4 + g);
        __builtin_amdgcn_s_setprio(1);
#pragma unroll
        for (int m = 0; m < 2; m++)
#pragma unroll
            for (int n = 0; n < 4; n++)
#pragma unroll
                for (int ks = 0; ks < 2; ks++)
                    acc[m][n] = mfma16(af[m][ks], bfr[n][ks], acc[m][n]);
        __builtin_amdgcn_s_setprio(0);
        __syncthreads();
    }

    // epilogue: C row = row0 + wr*32 + m*16 + g*4 + r ; col = col0 + wc*64 + n*16 + c
#pragma unroll
    for (int n = 0; n < 4; n++) {
        const int gc = col0 + wc * 64 + n * 16 + c;
        const float bvl = bias[gc] * bscale;
        const int h = gc >> 6, d = gc & 63;
#pragma unroll
        for (int m = 0; m < 2; m++) {
            const int gr = row0 + wr * 32 + m * 16 + g * 4;
            if (EPI == 2) {
                float* O = (float*)outp;
#pragma unroll
                for (int r = 0; r < 4; r++) O[(gr + r) * 1024 + gc] = acc[m][n][r] + bvl;
            } else {
                const int b = gr >> 11, sr = gr & 2047;
                short* O = (short*)outp;
                if (EPI == 0) {
                    int base = ((b * 16 + h) * 2048 + sr) * 64 + d;
#pragma unroll
                    for (int r = 0; r < 4; r++) O[base + r * 64] = f2bf(acc[m][n][r] + bvl);
                } else {
                    s4v vv;
#pragma unroll
                    for (int r = 0; r < 4; r++) vv[r] = f2bf(acc[m][n][r] + bvl);
                    *reinterpret_cast<s4v*>(O + ((b * 16 + h) * 64 + d) * 2048 + sr) = vv;
                }
            }
        }
    }
}

// fused QKV projection: grid (64, 24); XCD-chunked swizzle; y-slot selects Q/K/V
__global__ __launch_bounds__(256, 2) void k_gemm3(
    const short* __restrict__ A,
    const short* __restrict__ WqT, const short* __restrict__ WkT, const short* __restrict__ WvT,
    const float* __restrict__ bq, const float* __restrict__ bk, const float* __restrict__ bv,
    short* __restrict__ Qs, short* __restrict__ Kst, short* __restrict__ Vts, float scq)
{
    __shared__ alignas(16) short As[64 * 64];
    __shared__ alignas(16) short Bs[128 * 64];
    const int bid = blockIdx.y * 64 + blockIdx.x;       // 1536 blocks
    const int sw = (bid & 7) * 192 + (bid >> 3);        // bijective (1536%8==0)
    const int row0 = (sw & 63) * 64;
    const int yy = sw >> 6;                             // 0..23
    const int which = yy >> 3;
    const int col0 = (yy & 7) * 128;
    if (which == 0)
        gemm_body<0>(A, WqT, bq, Qs, scq, row0, col0, As, Bs);
    else if (which == 1)
        gemm_body<0>(A, WkT, bk, Kst, 1.f, row0, col0, As, Bs);
    else
        gemm_body<1>(A, WvT, bv, Vts, 1.f, row0, col0, As, Bs);
}

// final projection: grid (64, 8), XCD-chunked swizzle
__global__ __launch_bounds__(256, 2) void k_gemmO(
    const short* __restrict__ A, const short* __restrict__ Bt,
    const float* __restrict__ bias, float* __restrict__ outp)
{
    __shared__ alignas(16) short As[64 * 64];
    __shared__ alignas(16) short Bs[128 * 64];
    const int bid = blockIdx.y * 64 + blockIdx.x;       // 512 blocks
    const int sw = (bid & 7) * 64 + (bid >> 3);
    gemm_body<2>(A, Bt, bias, outp, 1.f, (sw & 63) * 64, (sw >> 6) * 128, As, Bs);
}

// ---------------- flash attention, 16x16 MFMA, linear-chunk LDS ----------------
// Q,K: [B,H,S,64] bf16 (Q pre-scaled by 0.125*log2e), Vt: [B,H,64,S] bf16,
// bb: 0.5*log2e*binding bf16 [S,S].  Ob: [B,S,1024] bf16.
// Grid (32, 32) XCD-chunk-swizzled: 4 waves x 16 q-rows, KV tile 64, dbuf LDS.
// LDS chunk layout: 16B chunk (row=16n+c, dchunk=4ks+g) at idx = n<<7|ks<<6|g<<4|c,
// so every frag read is base + lane*16B + imm (no addr math, contiguous).
// Bias enters as QK accumulator init; softmax in exp2 domain vs fixed mrun=20
// (post-PV corrected if exceeded); row-sum via ones-fragment MFMA.
__global__ __launch_bounds__(256, 4) void k_attn(
    const short* __restrict__ Q, const short* __restrict__ K,
    const short* __restrict__ Vt, const short* __restrict__ bb,
    short* __restrict__ Ob)
{
    __shared__ alignas(16) short Ks[2][64 * 64];
    __shared__ alignas(16) short Vs[2][64 * 64];
    __shared__ alignas(16) short Ps[4][16 * 64];
    const int t = threadIdx.x, lane = t & 63;
    const int wv = t >> 6, g = lane >> 4, c = lane & 15;
    const int bid = blockIdx.y * 32 + blockIdx.x;       // 1024 blocks
    const int sw = (bid & 7) * 128 + (bid >> 3);        // XCD chunk: 4 bh per XCD
    const int qt = sw & 31, bh = sw >> 5;
    const int b = bh >> 4, h = bh & 15;
    const short* Qb = Q + bh * 2048 * 64;
    const short* Kb = K + bh * 2048 * 64;
    const short* Vb = Vt + bh * 64 * 2048;
    const int q0 = qt * 64 + wv * 16;

    // Q fragments (B-operand): lane holds Q[q0+c][32ks+8g .. +7]
    bfv8 qf[2];
#pragma unroll
    for (int ks = 0; ks < 2; ks++)
        qf[ks] = *reinterpret_cast<const bfv8*>(Qb + (q0 + c) * 64 + ks * 32 + g * 8);

    const f32x4 z4 = {0.f, 0.f, 0.f, 0.f};
    f32x4 oa[4];             // [nd]; elem r: O^T[d=nd*16+4g+r][q=q0+c]
#pragma unroll
    for (int nd = 0; nd < 4; nd++) oa[nd] = z4;
    f32x4 lacc = z4;         // row-sum accumulator via ones-MFMA
    float mrun = 20.0f;      // fixed max-estimate (logits bounded ~|9|)

    // ones A-fragment for the row-sum MFMA
    s8v ob_;
#pragma unroll
    for (int i = 0; i < 8; i++) ob_[i] = (short)0x3F80;
    const bfv8 ones = __builtin_bit_cast(bfv8, ob_);

    // staging: 512 chunks/tile, 2 per thread; chunk idx = n<<7|ks<<6|g<<4|c
    const short* kp[2]; const short* vp[2]; int dst8[2];
#pragma unroll
    for (int j = 0; j < 2; j++) {
        int idx = j * 256 + t;
        int row = 16 * (idx >> 7) + (idx & 15);   // K row (or V^T d-row)
        int jc = (idx >> 4) & 7;                  // 8-elem chunk in d (or k)
        kp[j] = Kb + row * 64 + jc * 8;
        vp[j] = Vb + row * 2048 + jc * 8;
        dst8[j] = idx * 8;
    }
    auto stageK = [&](int buf) {
        gload16(kp[0], &Ks[buf][dst8[0]]);
        gload16(kp[1], &Ks[buf][dst8[1]]);
        kp[0] += 4096; kp[1] += 4096;
    };
    auto stageV = [&](int buf) {
        gload16(vp[0], &Vs[buf][dst8[0]]);
        gload16(vp[1], &Vs[buf][dst8[1]]);
        vp[0] += 64; vp[1] += 64;
    };
    const short* bbp = bb + (size_t)(q0 + c) * 2048 + 4 * g;
    s4v bnC[4], bnN[4];
    auto ldbias = [&](s4v* d) {
#pragma unroll
        for (int n = 0; n < 4; n++) d[n] = *reinterpret_cast<const s4v*>(bbp + n * 16);
        bbp += 64;
    };

    // P-tile addresses (per-wave private, linear-chunk layout)
    short* Pw = &Ps[wv][0];
    short* pwr = Pw + (g >> 1) * 128 + c * 8 + 4 * (g & 1);  // write base (+n*256)
    const short* prd = Pw + lane * 8;                        // read base (+512 for ks=1)

    // prologue
    stageV(0);
    stageK(0);
    ldbias(bnC);
    __syncthreads();

    for (int kt = 0; kt < 32; ++kt) {
        const int cur = kt & 1;
        // consume bias prefetch -> f32 C-init fragments
        f32x4 cb[4];
#pragma unroll
        for (int n = 0; n < 4; n++)
#pragma unroll
            for (int r = 0; r < 4; r++) cb[n][r] = bf2f(bnC[n][r]);
        if (kt < 31) {
            stageV(cur ^ 1);
            stageK(cur ^ 1);
            ldbias(bnN);
        }
        const short* Kl = &Ks[cur][0] + lane * 8;
        const short* Vl = &Vs[cur][0] + lane * 8;

        // QK^T with bias as accumulator init: sc[n][r] = bias + QK, k=16n+4g+r
        f32x4 sc[4];
        __builtin_amdgcn_s_setprio(1);
#pragma unroll
        for (int n = 0; n < 4; n++) {
            bfv8 k0 = *reinterpret_cast<const bfv8*>(Kl + n * 1024);
            bfv8 k1 = *reinterpret_cast<const bfv8*>(Kl + n * 1024 + 512);
            sc[n] = mfma16(k0, qf[0], cb[n]);
            sc[n] = mfma16(k1, qf[1], sc[n]);
        }
        __builtin_amdgcn_s_setprio(0);

        // speculative exp2 against running max-estimate
#pragma unroll
        for (int n = 0; n < 4; n++)
#pragma unroll
            for (int r = 0; r < 4; r++)
                sc[n][r] = __builtin_amdgcn_exp2f(sc[n][r] - mrun);

        // pack P -> per-wave linear-chunk LDS tile
#pragma unroll
        for (int n = 0; n < 4; n++) {
            uint2 wp;
            wp.x = cvtpk(sc[n][0], sc[n][1]);
            wp.y = cvtpk(sc[n][2], sc[n][3]);
            *reinterpret_cast<uint2*>(pwr + n * 256) = wp;
        }

        // PV + row-sum: oa[nd] += V^T-frag x P-frag ; lacc += ones x P-frag
        bfv8 pb0 = *reinterpret_cast<const bfv8*>(prd);
        bfv8 pb1 = *reinterpret_cast<const bfv8*>(prd + 512);
        __builtin_amdgcn_s_setprio(1);
#pragma unroll
        for (int nd = 0; nd < 4; nd++) {
            bfv8 v0 = *reinterpret_cast<const bfv8*>(Vl + nd * 1024);
            bfv8 v1 = *reinterpret_cast<const bfv8*>(Vl + nd * 1024 + 512);
            oa[nd] = mfma16(v0, pb0, oa[nd]);
            oa[nd] = mfma16(v1, pb1, oa[nd]);
        }
        lacc = mfma16(ones, pb0, lacc);
        lacc = mfma16(ones, pb1, lacc);
        __builtin_amdgcn_s_setprio(0);

        // deferred-max safety check in pe-domain (2^11.5 = 2896)
        float t0 = fmaxf(max3f(sc[0][0], sc[0][1], sc[0][2]), sc[0][3]);
        float t1 = fmaxf(max3f(sc[1][0], sc[1][1], sc[1][2]), sc[1][3]);
        float t2 = fmaxf(max3f(sc[2][0], sc[2][1], sc[2][2]), sc[2][3]);
        float t3 = fmaxf(max3f(sc[3][0], sc[3][1], sc[3][2]), sc[3][3]);
        float pemax = fmaxf(max3f(t0, t1, t2), t3);
        if (!__all(pemax <= 2896.0f)) {   // rare: raise mrun, correct oa & lacc
            float rmax = fmaxf(pemax, __shfl_xor(pemax, 16));
            rmax = fmaxf(rmax, __shfl_xor(rmax, 32));
            if (rmax > 2896.0f) {
                const float corr = 1.0f / rmax;
                mrun += __log2f(rmax);
#pragma unroll
                for (int nd = 0; nd < 4; nd++)
#pragma unroll
                    for (int r = 0; r < 4; r++) oa[nd][r] *= corr;
#pragma unroll
                for (int r = 0; r < 4; r++) lacc[r] *= corr;
            }
        }
#pragma unroll
        for (int n = 0; n < 4; n++) bnC[n] = bnN[n];
        __syncthreads();
    }

    // epilogue: O^T frag -> Ob[B,S,1024], 8B stores; d = nd*16 + 4g + r
    const float rl = 1.0f / lacc[0];
    const size_t srow = (size_t)(b * 2048 + q0 + c);
#pragma unroll
    for (int nd = 0; nd < 4; nd++) {
        s4v st;
#pragma unroll
        for (int r = 0; r < 4; r++) st[r] = f2bf(oa[nd][r] * rl);
        *reinterpret_cast<s4v*>(Ob + srow * 1024 + h * 64 + nd * 16 + 4 * g) = st;
    }
}

extern "C" void kernel_launch(void* const* d_in, const int* in_sizes, int n_in,
                              void* d_out, int out_size, void* d_ws, size_t ws_size,
                              hipStream_t stream)
{
    (void)in_sizes; (void)n_in; (void)out_size; (void)ws_size;
    const float* x    = (const float*)d_in[0];
    const float* bind = (const float*)d_in[1];
    const float* Wq   = (const float*)d_in[2];
    const float* bq   = (const float*)d_in[3];
    const float* Wk   = (const float*)d_in[4];
    const float* bk   = (const float*)d_in[5];
    const float* Wv   = (const float*)d_in[6];
    const float* bv   = (const float*)d_in[7];
    const float* Wo   = (const float*)d_in[8];
    const float* bo   = (const float*)d_in[9];

    char* ws = (char*)d_ws;
    const size_t MB = (size_t)1 << 20;
    short* xb   = (short*)(ws + 0 * MB);   // 8 MiB  x as bf16
    short* Wqt  = (short*)(ws + 8 * MB);   // 2 MiB  each, [n][k] bf16
    short* Wkt  = (short*)(ws + 10 * MB);
    short* Wvt  = (short*)(ws + 12 * MB);
    short* Wot  = (short*)(ws + 14 * MB);
    short* bbm  = (short*)(ws + 16 * MB);  // 8 MiB  0.5*log2e*binding bf16
    short* Qs   = (short*)(ws + 24 * MB);  // 8 MiB  [B,H,S,64]
    short* Kst  = (short*)(ws + 32 * MB);  // 8 MiB  [B,H,S,64]
    short* Vts  = (short*)(ws + 40 * MB);  // 8 MiB  [B,H,64,S]
    short* Obuf = (short*)(ws + 48 * MB);  // 8 MiB  [B,S,1024]

    const float LOG2E = 1.4426950408889634f;
    const float SCQ = 0.125f * LOG2E;   // hd^-0.5 * log2e, folded into Wq/bq
    const float SCB = 0.5f * LOG2E;     // binding_bias * log2e

    k_cvt<<<2048, 256, 0, stream>>>(x, xb, 1.f);
    k_cvt<<<2048, 256, 0, stream>>>(bind, bbm, SCB);
    k_transpose4<<<dim3(32, 32, 4), 256, 0, stream>>>(Wq, Wk, Wv, Wo,
                                                      Wqt, Wkt, Wvt, Wot, SCQ);
    k_gemm3<<<dim3(64, 24), 256, 0, stream>>>(xb, Wqt, Wkt, Wvt, bq, bk, bv,
                                              Qs, Kst, Vts, SCQ);
    k_attn<<<dim3(32, 32), 256, 0, stream>>>(Qs, Kst, Vts, bbm, Obuf);
    k_gemmO<<<dim3(64, 8), 256, 0, stream>>>(Obuf, Wot, bo, (float*)d_out);
}

// Round 8
// 151.191 us; speedup vs baseline: 1.3157x; 1.3157x over previous
//
#include <hip/hip_runtime.h>

#define DEV static __device__ __forceinline__

typedef __attribute__((ext_vector_type(4))) float f32x4;
typedef __attribute__((ext_vector_type(8))) __bf16 bfv8;
typedef __attribute__((ext_vector_type(8))) short s8v;
typedef __attribute__((ext_vector_type(4))) short s4v;

DEV short f2bf(float f) {
    unsigned u = __float_as_uint(f);
    u = (u + 0x7fffu + ((u >> 16) & 1u)) >> 16;
    return (short)u;
}
DEV float bf2f(short s) { return __uint_as_float(((unsigned)(unsigned short)s) << 16); }

DEV void gload16(const void* g, void* l) {
    __builtin_amdgcn_global_load_lds(
        (const __attribute__((address_space(1))) void*)g,
        (__attribute__((address_space(3))) void*)l, 16, 0, 0);
}

DEV f32x4 mfma16(bfv8 a, bfv8 b, f32x4 c) {
    return __builtin_amdgcn_mfma_f32_16x16x32_bf16(a, b, c, 0, 0, 0);
}

DEV float max3f(float a, float b, float c) {
    float d;
    asm("v_max3_f32 %0, %1, %2, %3" : "=v"(d) : "v"(a), "v"(b), "v"(c));
    return d;
}
DEV unsigned cvtpk(float lo, float hi) {
    unsigned w;
    asm("v_cvt_pk_bf16_f32 %0, %1, %2" : "=v"(w) : "v"(lo), "v"(hi));
    return w;
}

// LDS tile layout: [row][8 slots of 8 bf16], physical slot = logical slot ^ (row&7)
DEV bfv8 ldsfrag(const short* base, int row, int slog) {
    int sp = slog ^ (row & 7);
    return *reinterpret_cast<const bfv8*>(base + row * 64 + sp * 8);
}

// ---------------- f32 -> bf16 elementwise (8 elems/thread, exact-fit grid) ----
__global__ void k_cvt(const float* __restrict__ in, short* __restrict__ out, float s) {
    int i = blockIdx.x * blockDim.x + threadIdx.x;
    const float4* p = (const float4*)in + (size_t)i * 2;
    float4 a = p[0], b = p[1];
    s8v o;
    o[0] = f2bf(a.x * s); o[1] = f2bf(a.y * s); o[2] = f2bf(a.z * s); o[3] = f2bf(a.w * s);
    o[4] = f2bf(b.x * s); o[5] = f2bf(b.y * s); o[6] = f2bf(b.z * s); o[7] = f2bf(b.w * s);
    reinterpret_cast<s8v*>(out)[i] = o;
}

// ---------------- all four W [1024x1024] f32 -> Wt [n][k] bf16 (z selects) -----
__global__ void k_transpose4(
    const float* __restrict__ W0, const float* __restrict__ W1,
    const float* __restrict__ W2, const float* __restrict__ W3,
    short* __restrict__ T0, short* __restrict__ T1,
    short* __restrict__ T2, short* __restrict__ T3, float s0)
{
    __shared__ float tl[32][33];
    const int z = blockIdx.z;
    const float* W = z == 0 ? W0 : z == 1 ? W1 : z == 2 ? W2 : W3;
    short* Wt = z == 0 ? T0 : z == 1 ? T1 : z == 2 ? T2 : T3;
    const float s = z == 0 ? s0 : 1.f;
    int tx = threadIdx.x & 31, ty = threadIdx.x >> 5;
    int nb = blockIdx.x * 32, kb = blockIdx.y * 32;
#pragma unroll
    for (int i = 0; i < 4; i++)
        tl[ty + i * 8][tx] = W[(kb + ty + i * 8) * 1024 + nb + tx];
    __syncthreads();
#pragma unroll
    for (int i = 0; i < 4; i++)
        Wt[(nb + ty + i * 8) * 1024 + kb + tx] = f2bf(tl[tx][ty + i * 8] * s);
}

// ---------------- GEMM core (BM=64 BN=128 BK=64, 4 waves 2Mx2N) ---------------
// epi 0: bf16 out [B,H,S,Hd]; epi 1: bf16 out [B,H,Hd,S] (V^T); epi 2: f32 row-major.
template <int EPI>
DEV void gemm_body(const short* __restrict__ A, const short* __restrict__ Bt,
                   const float* __restrict__ bias, void* __restrict__ outp,
                   float bscale, int row0, int col0, short* As, short* Bs)
{
    const int t = threadIdx.x, lane = t & 63;
    const int wv = t >> 6, wr = wv >> 1, wc = wv & 1;
    const int g = lane >> 4, c = lane & 15;

    const f32x4 z4 = {0.f, 0.f, 0.f, 0.f};
    f32x4 acc[2][4];
#pragma unroll
    for (int m = 0; m < 2; m++)
#pragma unroll
        for (int n = 0; n < 4; n++) acc[m][n] = z4;

    for (int kt = 0; kt < 16; ++kt) {
        const int k0 = kt * 64;
        const short* Ag = A + row0 * 1024 + k0;
        const short* Bg = Bt + col0 * 1024 + k0;
#pragma unroll
        for (int j = 0; j < 2; j++) {
            int idx = j * 256 + t;
            int row = idx >> 3, sp = idx & 7, sl = sp ^ (row & 7);
            gload16(Ag + row * 1024 + sl * 8, As + idx * 8);
        }
#pragma unroll
        for (int j = 0; j < 4; j++) {
            int idx = j * 256 + t;
            int row = idx >> 3, sp = idx & 7, sl = sp ^ (row & 7);
            gload16(Bg + row * 1024 + sl * 8, Bs + idx * 8);
        }
        __syncthreads();

        bfv8 af[2][2], bfr[4][2];
#pragma unroll
        for (int m = 0; m < 2; m++)
#pragma unroll
            for (int ks = 0; ks < 2; ks++)
                af[m][ks] = ldsfrag(As, wr * 32 + m * 16 + c, ks * 4 + g);
#pragma unroll
        for (int n = 0; n < 4; n++)
#pragma unroll
            for (int ks = 0; ks < 2; ks++)
                bfr[n][ks] = ldsfrag(Bs, wc * 64 + n * 16 + c, ks * 4 + g);
        __builtin_amdgcn_s_setprio(1);
#pragma unroll
        for (int m = 0; m < 2; m++)
#pragma unroll
            for (int n = 0; n < 4; n++)
#pragma unroll
                for (int ks = 0; ks < 2; ks++)
                    acc[m][n] = mfma16(af[m][ks], bfr[n][ks], acc[m][n]);
        __builtin_amdgcn_s_setprio(0);
        __syncthreads();
    }

    // epilogue: C row = row0 + wr*32 + m*16 + g*4 + r ; col = col0 + wc*64 + n*16 + c
#pragma unroll
    for (int n = 0; n < 4; n++) {
        const int gc = col0 + wc * 64 + n * 16 + c;
        const float bvl = bias[gc] * bscale;
        const int h = gc >> 6, d = gc & 63;
#pragma unroll
        for (int m = 0; m < 2; m++) {
            const int gr = row0 + wr * 32 + m * 16 + g * 4;
            if (EPI == 2) {
                float* O = (float*)outp;
#pragma unroll
                for (int r = 0; r < 4; r++) O[(gr + r) * 1024 + gc] = acc[m][n][r] + bvl;
            } else {
                const int b = gr >> 11, sr = gr & 2047;
                short* O = (short*)outp;
                if (EPI == 0) {
                    int base = ((b * 16 + h) * 2048 + sr) * 64 + d;
#pragma unroll
                    for (int r = 0; r < 4; r++) O[base + r * 64] = f2bf(acc[m][n][r] + bvl);
                } else {
                    s4v vv;
#pragma unroll
                    for (int r = 0; r < 4; r++) vv[r] = f2bf(acc[m][n][r] + bvl);
                    *reinterpret_cast<s4v*>(O + ((b * 16 + h) * 64 + d) * 2048 + sr) = vv;
                }
            }
        }
    }
}

// fused QKV projection: grid (64, 24); y/8 selects Q/K/V
__global__ __launch_bounds__(256, 2) void k_gemm3(
    const short* __restrict__ A,
    const short* __restrict__ WqT, const short* __restrict__ WkT, const short* __restrict__ WvT,
    const float* __restrict__ bq, const float* __restrict__ bk, const float* __restrict__ bv,
    short* __restrict__ Qs, short* __restrict__ Kst, short* __restrict__ Vts, float scq)
{
    __shared__ alignas(16) short As[64 * 64];
    __shared__ alignas(16) short Bs[128 * 64];
    const int which = blockIdx.y >> 3;
    const int col0 = (blockIdx.y & 7) * 128;
    const int row0 = blockIdx.x * 64;
    if (which == 0)
        gemm_body<0>(A, WqT, bq, Qs, scq, row0, col0, As, Bs);
    else if (which == 1)
        gemm_body<0>(A, WkT, bk, Kst, 1.f, row0, col0, As, Bs);
    else
        gemm_body<1>(A, WvT, bv, Vts, 1.f, row0, col0, As, Bs);
}

// final projection
__global__ __launch_bounds__(256, 2) void k_gemmO(
    const short* __restrict__ A, const short* __restrict__ Bt,
    const float* __restrict__ bias, float* __restrict__ outp)
{
    __shared__ alignas(16) short As[64 * 64];
    __shared__ alignas(16) short Bs[128 * 64];
    gemm_body<2>(A, Bt, bias, outp, 1.f, blockIdx.x * 64, blockIdx.y * 128, As, Bs);
}

// ---------------- flash attention, swapped-operand (S^T / O^T) form ------------
// Q,K: [B,H,S,64] bf16 (Q pre-scaled by 0.125*log2e), Vt: [B,H,64,S] bf16,
// bb: 0.5*log2e*binding bf16 [S,S].  Ob: [B,S,1024] bf16.
// Grid: (S/64, B*H) = 1024 blocks. 4 waves x 16 q-rows. KV tile = 64, dbuf LDS.
// Softmax in exp2 domain with fixed max-estimate MEST (=20, > any logit);
// online-rescale kept as a post-PV correction (corr multiplies oa & lacc equally).
// Bias enters as the QK^T MFMA accumulator init; row-sum via ones-fragment MFMA
// (replaces 19 VALU adds + 2 serial shfl_xor per iter; lacc rows all = sum).
__global__ __launch_bounds__(256, 4) void k_attn(
    const short* __restrict__ Q, const short* __restrict__ K,
    const short* __restrict__ Vt, const short* __restrict__ bb,
    short* __restrict__ Ob)
{
    __shared__ alignas(16) short Ks[2][64 * 64];
    __shared__ alignas(16) short Vs[2][64 * 64];
    __shared__ alignas(16) short Ps[4][16 * 64];
    const int t = threadIdx.x, lane = t & 63;
    const int wv = t >> 6, g = lane >> 4, c = lane & 15;
    const int qt = blockIdx.x, bh = blockIdx.y;
    const int b = bh >> 4, h = bh & 15;
    const short* Qb = Q + bh * 2048 * 64;
    const short* Kb = K + bh * 2048 * 64;
    const short* Vb = Vt + bh * 64 * 2048;
    const int q0 = qt * 64 + wv * 16;

    // Q fragments (second-operand layout): lane holds Q row (q0+c)
    bfv8 qf[2];
#pragma unroll
    for (int ks = 0; ks < 2; ks++)
        qf[ks] = *reinterpret_cast<const bfv8*>(Qb + (q0 + c) * 64 + ks * 32 + g * 8);

    const f32x4 z4 = {0.f, 0.f, 0.f, 0.f};
    f32x4 oa[4];             // [nd]; elem r: O^T[d=nd*16+4g+r][q=q0+c]
#pragma unroll
    for (int nd = 0; nd < 4; nd++) oa[nd] = z4;
    f32x4 lacc = z4;         // row-sum accumulator via ones-MFMA
    float mrun = 20.0f;      // fixed max-estimate (logits bounded ~|12|)

    // ones A-fragment for the row-sum MFMA
    s8v ob_;
#pragma unroll
    for (int i = 0; i < 8; i++) ob_[i] = (short)0x3F80;
    const bfv8 ones = __builtin_bit_cast(bfv8, ob_);

    // staging pointers (strength-reduced)
    const int idx0 = t, idx1 = 256 + t;
    const int r0 = idx0 >> 3, s0 = ((idx0 & 7) ^ (r0 & 7)) * 8;
    const int r1 = idx1 >> 3, s1 = ((idx1 & 7) ^ (r1 & 7)) * 8;
    const short* kp0 = Kb + r0 * 64 + s0;
    const short* kp1 = Kb + r1 * 64 + s1;
    const short* vp0 = Vb + r0 * 2048 + s0;
    const short* vp1 = Vb + r1 * 2048 + s1;
    const short* bbp = bb + (size_t)(q0 + c) * 2048 + 4 * g;

    // hoisted P-tile LDS addresses
    char* Pb = (char*)&Ps[wv][0];
    const int rx = c & 7;
    char* pw[4];
#pragma unroll
    for (int n = 0; n < 4; n++)
        pw[n] = Pb + c * 128 + (((2 * n + (g >> 1)) ^ rx) << 4) + ((g & 1) << 3);
    const char* pr0 = Pb + c * 128 + ((g ^ rx) << 4);
    const char* pr1 = Pb + c * 128 + (((4 + g) ^ rx) << 4);

    // initial stage + bias prefetch
    gload16(kp0, &Ks[0][idx0 * 8]);
    gload16(kp1, &Ks[0][idx1 * 8]);
    gload16(vp0, &Vs[0][idx0 * 8]);
    gload16(vp1, &Vs[0][idx1 * 8]);
    kp0 += 4096; kp1 += 4096; vp0 += 64; vp1 += 64;
    s4v bn[4];
#pragma unroll
    for (int n = 0; n < 4; n++) bn[n] = *reinterpret_cast<const s4v*>(bbp + n * 16);
    bbp += 64;
    __syncthreads();

    for (int kt = 0; kt < 32; ++kt) {
        const int cur = kt & 1;
        // consume bias prefetch -> f32 C-init fragments
        f32x4 cb[4];
#pragma unroll
        for (int n = 0; n < 4; n++)
#pragma unroll
            for (int r = 0; r < 4; r++) cb[n][r] = bf2f(bn[n][r]);
        if (kt < 31) {
            const int nb = cur ^ 1;
            gload16(kp0, &Ks[nb][idx0 * 8]);
            gload16(kp1, &Ks[nb][idx1 * 8]);
            gload16(vp0, &Vs[nb][idx0 * 8]);
            gload16(vp1, &Vs[nb][idx1 * 8]);
            kp0 += 4096; kp1 += 4096; vp0 += 64; vp1 += 64;
#pragma unroll
            for (int n = 0; n < 4; n++) bn[n] = *reinterpret_cast<const s4v*>(bbp + n * 16);
            bbp += 64;
        }

        const short* Kc = &Ks[cur][0];
        const short* Vc = &Vs[cur][0];

        // S^T tile with bias as accumulator init: sc[n][r] = bias + QK
        f32x4 sc[4];
        __builtin_amdgcn_s_setprio(1);
#pragma unroll
        for (int n = 0; n < 4; n++) {
            bfv8 k0 = ldsfrag(Kc, n * 16 + c, g);
            bfv8 k1 = ldsfrag(Kc, n * 16 + c, 4 + g);
            sc[n] = mfma16(k0, qf[0], cb[n]);
            sc[n] = mfma16(k1, qf[1], sc[n]);
        }
        __builtin_amdgcn_s_setprio(0);

        // speculative exp2 against running max-estimate (no branch wait)
#pragma unroll
        for (int n = 0; n < 4; n++)
#pragma unroll
            for (int r = 0; r < 4; r++)
                sc[n][r] = __builtin_amdgcn_exp2f(sc[n][r] - mrun);

        // pack P -> swizzled per-wave LDS tile [16 q][64 k]
#pragma unroll
        for (int n = 0; n < 4; n++) {
            uint2 wp;
            wp.x = cvtpk(sc[n][0], sc[n][1]);
            wp.y = cvtpk(sc[n][2], sc[n][3]);
            *reinterpret_cast<uint2*>(pw[n]) = wp;
        }

        // PV (swapped) + row-sum: oa[nd] += V^T-frag x P-frag ; lacc += ones x P
        bfv8 pa0 = *reinterpret_cast<const bfv8*>(pr0);
        bfv8 pa1 = *reinterpret_cast<const bfv8*>(pr1);
        __builtin_amdgcn_s_setprio(1);
#pragma unroll
        for (int nd = 0; nd < 4; nd++) {
            bfv8 v0 = ldsfrag(Vc, nd * 16 + c, g);
            bfv8 v1 = ldsfrag(Vc, nd * 16 + c, 4 + g);
            oa[nd] = mfma16(v0, pa0, oa[nd]);
            oa[nd] = mfma16(v1, pa1, oa[nd]);
        }
        lacc = mfma16(ones, pa0, lacc);
        lacc = mfma16(ones, pa1, lacc);
        __builtin_amdgcn_s_setprio(0);

        // deferred-max safety check in pe-domain (2^11.5 = 2896)
        float t0 = fmaxf(max3f(sc[0][0], sc[0][1], sc[0][2]), sc[0][3]);
        float t1 = fmaxf(max3f(sc[1][0], sc[1][1], sc[1][2]), sc[1][3]);
        float t2 = fmaxf(max3f(sc[2][0], sc[2][1], sc[2][2]), sc[2][3]);
        float t3 = fmaxf(max3f(sc[3][0], sc[3][1], sc[3][2]), sc[3][3]);
        float pemax = fmaxf(max3f(t0, t1, t2), t3);
        if (!__all(pemax <= 2896.0f)) {   // rare: raise mrun, correct oa & lacc
            float rmax = fmaxf(pemax, __shfl_xor(pemax, 16));
            rmax = fmaxf(rmax, __shfl_xor(rmax, 32));
            if (rmax > 2896.0f) {
                const float corr = 1.0f / rmax;
                mrun += __log2f(rmax);
#pragma unroll
                for (int nd = 0; nd < 4; nd++)
#pragma unroll
                    for (int r = 0; r < 4; r++) oa[nd][r] *= corr;
#pragma unroll
                for (int r = 0; r < 4; r++) lacc[r] *= corr;
            }
        }
        __syncthreads();
    }

    // epilogue: O^T frag -> Ob[B,S,1024], 8B stores
    const float rl = 1.0f / lacc[0];
    const size_t srow = (size_t)(b * 2048 + q0 + c);
#pragma unroll
    for (int nd = 0; nd < 4; nd++) {
        s4v st;
#pragma unroll
        for (int r = 0; r < 4; r++) st[r] = f2bf(oa[nd][r] * rl);
        *reinterpret_cast<s4v*>(Ob + srow * 1024 + h * 64 + nd * 16 + 4 * g) = st;
    }
}

extern "C" void kernel_launch(void* const* d_in, const int* in_sizes, int n_in,
                              void* d_out, int out_size, void* d_ws, size_t ws_size,
                              hipStream_t stream)
{
    (void)in_sizes; (void)n_in; (void)out_size; (void)ws_size;
    const float* x    = (const float*)d_in[0];
    const float* bind = (const float*)d_in[1];
    const float* Wq   = (const float*)d_in[2];
    const float* bq   = (const float*)d_in[3];
    const float* Wk   = (const float*)d_in[4];
    const float* bk   = (const float*)d_in[5];
    const float* Wv   = (const float*)d_in[6];
    const float* bv   = (const float*)d_in[7];
    const float* Wo   = (const float*)d_in[8];
    const float* bo   = (const float*)d_in[9];

    char* ws = (char*)d_ws;
    const size_t MB = (size_t)1 << 20;
    short* xb   = (short*)(ws + 0 * MB);   // 8 MiB  x as bf16
    short* Wqt  = (short*)(ws + 8 * MB);   // 2 MiB  each, [n][k] bf16
    short* Wkt  = (short*)(ws + 10 * MB);
    short* Wvt  = (short*)(ws + 12 * MB);
    short* Wot  = (short*)(ws + 14 * MB);
    short* bbm  = (short*)(ws + 16 * MB);  // 8 MiB  0.5*log2e*binding bf16
    short* Qs   = (short*)(ws + 24 * MB);  // 8 MiB  [B,H,S,64]
    short* Kst  = (short*)(ws + 32 * MB);  // 8 MiB  [B,H,S,64]
    short* Vts  = (short*)(ws + 40 * MB);  // 8 MiB  [B,H,64,S]
    short* Obuf = (short*)(ws + 48 * MB);  // 8 MiB  [B,S,1024]

    const float LOG2E = 1.4426950408889634f;
    const float SCQ = 0.125f * LOG2E;   // hd^-0.5 * log2e, folded into Wq/bq
    const float SCB = 0.5f * LOG2E;     // binding_bias * log2e

    k_cvt<<<2048, 256, 0, stream>>>(x, xb, 1.f);
    k_cvt<<<2048, 256, 0, stream>>>(bind, bbm, SCB);
    k_transpose4<<<dim3(32, 32, 4), 256, 0, stream>>>(Wq, Wk, Wv, Wo,
                                                      Wqt, Wkt, Wvt, Wot, SCQ);
    k_gemm3<<<dim3(64, 24), 256, 0, stream>>>(xb, Wqt, Wkt, Wvt, bq, bk, bv,
                                              Qs, Kst, Vts, SCQ);
    k_attn<<<dim3(32, 32), 256, 0, stream>>>(Qs, Kst, Vts, bbm, Obuf);
    k_gemmO<<<dim3(64, 8), 256, 0, stream>>>(Obuf, Wot, bo, (float*)d_out);
}